// Round 1
// 302.120 us; speedup vs baseline: 1.0776x; 1.0776x over previous
//
#include <hip/hip_runtime.h>
#include <math.h>

// RBF kernel, N=M=8192, D=64, fp32 in/out.
// v2: two-pass. Pass 1 pre-scales rows by 1/softplus(l), splits to bf16 hi/lo
// (3-GEMM split preserves d2 err ~1e-3 vs 0.04 budget), computes exact fp32
// norms. Pass 2: barrier-free MFMA GEMM with SWAPPED operand order
// (mfma(B,A): lane holds 4 consecutive output COLUMNS of one row), exp in
// registers, per-wave 64x64 LDS transpose (XOR chunk swizzle -> LDS BW floor),
// and dwordx4 stores with 4x256B contiguous segments per instruction.
// Theory: v1's 325us == 268MB / 825GB/s effective write BW from scalar
// stores scattering 4x64B segments at 32KB row stride; fills prove the write
// path does 6.4TB/s at 10% occupancy. Target: write-bound ~55-90us.
#define NN 8192
#define MM 8192
#define DD 64
#define BM 128
#define BN 128

typedef __bf16 bf16x8 __attribute__((ext_vector_type(8)));
typedef __bf16 bf16x4 __attribute__((ext_vector_type(4)));
typedef float f32x4 __attribute__((ext_vector_type(4)));

// Packed pre-scaled panels (bf16 hi/lo) + exact norms. 4.25 MB static.
__device__ __align__(16) __bf16 g_Xh[(size_t)NN * DD];
__device__ __align__(16) __bf16 g_Xl[(size_t)NN * DD];
__device__ __align__(16) __bf16 g_Yh[(size_t)MM * DD];
__device__ __align__(16) __bf16 g_Yl[(size_t)MM * DD];
__device__ __align__(16) float  g_xn[NN];
__device__ __align__(16) float  g_yn[MM];

__device__ __forceinline__ float softplus_f(float x) {
    // logaddexp(x, 0) = max(x,0) + log1p(exp(-|x|)), fp32-stable
    return fmaxf(x, 0.0f) + log1pf(exp2f(-fabsf(x) * 1.4426950408889634f));
}

// ---- pass 1: one wave per 64 rows; each thread owns one row ----
__global__ __launch_bounds__(64)
void prep_kernel(const float* __restrict__ X, const float* __restrict__ X2,
                 const float* __restrict__ raw_l) {
    __shared__ float ls[DD];
    const int t = threadIdx.x;
    ls[t] = 1.0f / softplus_f(raw_l[t]);
    __syncthreads();

    const int row = blockIdx.x * 64 + t;  // 0..16383; block 128 is the X/X2 boundary
    const bool isX = row < NN;
    const int r = isX ? row : row - NN;
    const float* src = (isX ? X : X2) + (size_t)r * DD;
    __bf16* dh = (isX ? g_Xh : g_Yh) + (size_t)r * DD;
    __bf16* dl = (isX ? g_Xl : g_Yl) + (size_t)r * DD;

    float s = 0.0f;
#pragma unroll
    for (int j = 0; j < 16; ++j) {
        float4 a = *(const float4*)(src + 4 * j);
        a.x *= ls[4 * j + 0];
        a.y *= ls[4 * j + 1];
        a.z *= ls[4 * j + 2];
        a.w *= ls[4 * j + 3];
        bf16x4 h, l;
        h[0] = (__bf16)a.x; l[0] = (__bf16)(a.x - (float)h[0]);
        h[1] = (__bf16)a.y; l[1] = (__bf16)(a.y - (float)h[1]);
        h[2] = (__bf16)a.z; l[2] = (__bf16)(a.z - (float)h[2]);
        h[3] = (__bf16)a.w; l[3] = (__bf16)(a.w - (float)h[3]);
        *(bf16x4*)(dh + 4 * j) = h;
        *(bf16x4*)(dl + 4 * j) = l;
        s = fmaf(a.x, a.x, s);
        s = fmaf(a.y, a.y, s);
        s = fmaf(a.z, a.z, s);
        s = fmaf(a.w, a.w, s);
    }
    if (isX) g_xn[r] = s; else g_yn[r] = s;
}

// ---- pass 2: barrier-free MFMA + transposed coalesced epilogue ----
__global__ __launch_bounds__(256, 2)
void rbf_gemm_kernel(const float* __restrict__ raw_v, float* __restrict__ out) {
    // per-wave private 64x64 f32 transpose tile (4 x 16KB = 64KB -> 2 blocks/CU)
    __shared__ __align__(16) float ctile[4][64 * 64];

    const int t    = threadIdx.x;
    const int lane = t & 63;
    const int w    = t >> 6;       // wave 0..3
    const int q    = lane >> 4;    // 0..3
    const int r16  = lane & 15;    // 0..15

    const int row0 = blockIdx.y * BM + (w >> 1) * 64;  // global out-row base
    const int col0 = blockIdx.x * BN + (w & 1) * 64;   // global out-col base

    f32x4 acc[4][4];
#pragma unroll
    for (int mi = 0; mi < 4; ++mi)
#pragma unroll
        for (int ni = 0; ni < 4; ++ni)
#pragma unroll
            for (int rr = 0; rr < 4; ++rr) acc[mi][ni][rr] = 0.0f;

    const char* Xh = (const char*)g_Xh;
    const char* Xl = (const char*)g_Xl;
    const char* Yh = (const char*)g_Yh;
    const char* Yl = (const char*)g_Yl;

#pragma unroll
    for (int kc = 0; kc < 2; ++kc) {
        const int kb = kc * 64 + q * 16;  // byte offset in a 128B row: k0 = kc*32+q*8 elems
        bf16x8 ah[4], al[4], bh[4], bl[4];
#pragma unroll
        for (int i = 0; i < 4; ++i) {
            // per instruction the 64 lanes cover a contiguous 2KB region (16 rows x 128B)
            const size_t ao = (size_t)(row0 + i * 16 + r16) * 128 + kb;
            const size_t bo = (size_t)(col0 + i * 16 + r16) * 128 + kb;
            ah[i] = *(const bf16x8*)(Xh + ao);
            al[i] = *(const bf16x8*)(Xl + ao);
            bh[i] = *(const bf16x8*)(Yh + bo);
            bl[i] = *(const bf16x8*)(Yl + bo);
        }
        // SWAPPED order: D = B_op x A_op. Lane holds out[row = row0+mi*16+r16]
        // [cols = col0+ni*16+q*4 .. +3] -> 4 consecutive columns per lane.
        // 3-term split: hh + lh + hl (ll dropped; error ~1e-3 in d2).
#pragma unroll
        for (int mi = 0; mi < 4; ++mi)
#pragma unroll
            for (int ni = 0; ni < 4; ++ni) {
                acc[mi][ni] = __builtin_amdgcn_mfma_f32_16x16x32_bf16(bh[ni], ah[mi], acc[mi][ni], 0, 0, 0);
                acc[mi][ni] = __builtin_amdgcn_mfma_f32_16x16x32_bf16(bl[ni], ah[mi], acc[mi][ni], 0, 0, 0);
                acc[mi][ni] = __builtin_amdgcn_mfma_f32_16x16x32_bf16(bh[ni], al[mi], acc[mi][ni], 0, 0, 0);
            }
    }

    // ---- epilogue: d2 = max(xn+yn-2*cross,0); val = v*exp2(-0.5*log2e*d2) ----
    const float v  = softplus_f(raw_v[0]);
    const float ce = -0.5f * 1.4426950408889634f;

    float xs[4];
    f32x4 yn4[4];
#pragma unroll
    for (int mi = 0; mi < 4; ++mi) xs[mi] = g_xn[row0 + mi * 16 + r16];
#pragma unroll
    for (int ni = 0; ni < 4; ++ni) yn4[ni] = *(const f32x4*)(g_yn + col0 + ni * 16 + q * 4);

    float* cw = ctile[w];
    // write: lane row ml = mi*16+r16, logical 16B chunk ch = ni*4+q,
    // stored at ch ^ (ml&7): 8 lanes per 4-bank quad == LDS BW floor, no conflict.
#pragma unroll
    for (int mi = 0; mi < 4; ++mi) {
        const int ml = mi * 16 + r16;
#pragma unroll
        for (int ni = 0; ni < 4; ++ni) {
            f32x4 o;
#pragma unroll
            for (int rr = 0; rr < 4; ++rr) {
                float d2 = fmaxf(xs[mi] + yn4[ni][rr] - 2.0f * acc[mi][ni][rr], 0.0f);
                o[rr] = v * exp2f(ce * d2);
            }
            const int chs = (ni * 4 + q) ^ (ml & 7);
            *(f32x4*)&cw[ml * 64 + chs * 4] = o;
        }
    }

    // read back row-major and store: per instruction 4 rows x 256B contiguous.
#pragma unroll
    for (int j = 0; j < 16; ++j) {
        const int ml  = j * 4 + q;             // local row 0..63
        const int chs = r16 ^ (ml & 7);        // logical chunk r16, de-swizzled
        f32x4 o = *(const f32x4*)&cw[ml * 64 + chs * 4];
        float* dst = out + (size_t)(row0 + ml) * MM + col0 + r16 * 4;
        *(f32x4*)dst = o;
    }
}

extern "C" void kernel_launch(void* const* d_in, const int* in_sizes, int n_in,
                              void* d_out, int out_size, void* d_ws, size_t ws_size,
                              hipStream_t stream) {
    const float* X     = (const float*)d_in[0];
    const float* X2    = (const float*)d_in[1];
    const float* raw_l = (const float*)d_in[2];
    const float* raw_v = (const float*)d_in[3];
    float* out = (float*)d_out;

    prep_kernel<<<dim3((NN + MM) / 64), dim3(64), 0, stream>>>(X, X2, raw_l);
    rbf_gemm_kernel<<<dim3(MM / BN, NN / BM), dim3(256), 0, stream>>>(raw_v, out);
}